// Round 2
// baseline (6825.207 us; speedup 1.0000x reference)
//
#include <hip/hip_runtime.h>
#include <math.h>

#define CDIM 128
#define DDIM 32

static __device__ __forceinline__ float lrelu(float v) { return v >= 0.f ? v : 0.01f * v; }
static __device__ __forceinline__ float sigm(float x) {
    return __builtin_amdgcn_rcpf(1.f + __expf(-x));
}
static __device__ __forceinline__ float softp(float x) {
    // stable softplus: max(x,0) + log(1+exp(-|x|))
    return fmaxf(x, 0.f) + __logf(1.f + __expf(-fabsf(x)));
}

// ---------------- CSR build ----------------
__global__ void k_hist(const int* __restrict__ ei, int* __restrict__ counts, int E) {
    int stride = gridDim.x * blockDim.x;
    for (int e = blockIdx.x * blockDim.x + threadIdx.x; e < E; e += stride)
        atomicAdd(&counts[ei[E + e]], 1);  // dst = row 1
}

__global__ void k_scan1(const int* __restrict__ counts, int* __restrict__ excl,
                        int* __restrict__ bsum, int N) {
    __shared__ int sm[256];
    int t = threadIdx.x, idx = blockIdx.x * 256 + t;
    int v = (idx < N) ? counts[idx] : 0;
    sm[t] = v; __syncthreads();
    for (int off = 1; off < 256; off <<= 1) {
        int x = (t >= off) ? sm[t - off] : 0;
        __syncthreads();
        sm[t] += x;
        __syncthreads();
    }
    if (idx < N) excl[idx] = sm[t] - v;
    if (t == 255) bsum[blockIdx.x] = sm[255];
}

__global__ void k_scan2(const int* __restrict__ bsum, int* __restrict__ boff,
                        int* __restrict__ rowptr_end, int NB) {
    __shared__ int sm[256];
    int t = threadIdx.x;
    int v = (t < NB) ? bsum[t] : 0;
    sm[t] = v; __syncthreads();
    for (int off = 1; off < 256; off <<= 1) {
        int x = (t >= off) ? sm[t - off] : 0;
        __syncthreads();
        sm[t] += x;
        __syncthreads();
    }
    if (t < NB) boff[t] = sm[t] - v;
    if (t == 255) *rowptr_end = sm[255];  // == E
}

__global__ void k_scan3(int* __restrict__ rowptr, int* __restrict__ cur,
                        const int* __restrict__ boff, int N) {
    int idx = blockIdx.x * blockDim.x + threadIdx.x;
    if (idx < N) {
        int v = rowptr[idx] + boff[idx >> 8];
        rowptr[idx] = v;
        cur[idx] = v;
    }
}

__global__ void k_fill(const int* __restrict__ ei, int* __restrict__ cur,
                       int* __restrict__ src_s, int* __restrict__ eid_s, int E) {
    int stride = gridDim.x * blockDim.x;
    for (int e = blockIdx.x * blockDim.x + threadIdx.x; e < E; e += stride) {
        int d = ei[E + e];
        int pos = atomicAdd(&cur[d], 1);
        src_s[pos] = ei[e];   // src = row 0
        eid_s[pos] = e;
    }
}

// ---------------- layer 1: h0 = leaky([x, onehot] @ lin_W + b) ----------------
template <int ROWS>
__global__ void k_lin1(const float* __restrict__ x, const int* __restrict__ y,
                       const int* __restrict__ batch, const float* __restrict__ W,
                       const float* __restrict__ b, float* __restrict__ h0, int N) {
    __shared__ float xs[ROWS][CDIM];
    int c = threadIdx.x;             // 128 threads
    int n0 = blockIdx.x * ROWS;
    for (int r = 0; r < ROWS; r++) xs[r][c] = x[(n0 + r) * CDIM + c];
    __syncthreads();
    float acc[ROWS];
#pragma unroll
    for (int r = 0; r < ROWS; r++) {
        int cls = y[batch[n0 + r]];
        acc[r] = b[c] + W[(CDIM + cls) * CDIM + c];  // one-hot row select
    }
    for (int k = 0; k < CDIM; k++) {
        float w = W[k * CDIM + c];
#pragma unroll
        for (int r = 0; r < ROWS; r++) acc[r] = fmaf(xs[r][k], w, acc[r]);
    }
    for (int r = 0; r < ROWS; r++) h0[(n0 + r) * CDIM + c] = lrelu(acc[r]);
}

// ---------------- per-conv node GEMMs: P=h@Wf_d+bf, Q=h@Wf_s, R=h@Ws_d+bs, S=h@Ws_s ----------------
template <int ROWS>
__global__ void k_gemm4(const float* __restrict__ h, const float* __restrict__ Wf,
                        const float* __restrict__ Ws, const float* __restrict__ bf,
                        const float* __restrict__ bs, float* __restrict__ P,
                        float* __restrict__ Q, float* __restrict__ R,
                        float* __restrict__ S, int N) {
    __shared__ float hs[ROWS][CDIM];
    int c = threadIdx.x;
    int n0 = blockIdx.x * ROWS;
    for (int r = 0; r < ROWS; r++) hs[r][c] = h[(n0 + r) * CDIM + c];
    __syncthreads();
    float ap[ROWS], aq[ROWS], ar[ROWS], asv[ROWS];
    float vbf = bf[c], vbs = bs[c];
#pragma unroll
    for (int r = 0; r < ROWS; r++) { ap[r] = vbf; aq[r] = 0.f; ar[r] = vbs; asv[r] = 0.f; }
    for (int k = 0; k < CDIM; k++) {
        float wp = Wf[k * CDIM + c];
        float wq = Wf[(CDIM + k) * CDIM + c];
        float wr = Ws[k * CDIM + c];
        float wsv = Ws[(CDIM + k) * CDIM + c];
#pragma unroll
        for (int r = 0; r < ROWS; r++) {
            float hv = hs[r][k];
            ap[r] = fmaf(hv, wp, ap[r]);
            aq[r] = fmaf(hv, wq, aq[r]);
            ar[r] = fmaf(hv, wr, ar[r]);
            asv[r] = fmaf(hv, wsv, asv[r]);
        }
    }
    for (int r = 0; r < ROWS; r++) {
        int o = (n0 + r) * CDIM + c;
        P[o] = ap[r]; Q[o] = aq[r]; R[o] = ar[r]; S[o] = asv[r];
    }
}

// ---------------- edge aggregation (CSR, batched indices + 2-deep pipeline) ----------------
#define EDGE_LOAD(SUF, J)                                                            \
    {                                                                                \
        int s_ = __shfl(sL, (J));                                                    \
        int id_ = __shfl(idL, (J));                                                  \
        Q##SUF = Q[(size_t)s_ * CDIM + c];                                           \
        S##SUF = S[(size_t)s_ * CDIM + c];                                           \
        const float4* p_ = reinterpret_cast<const float4*>(eattr + (size_t)id_ * DDIM); \
        _Pragma("unroll") for (int d4 = 0; d4 < 8; d4++) e##SUF[d4] = p_[d4];        \
    }

#define EDGE_COMPUTE(SUF)                                                            \
    {                                                                                \
        float ef = 0.f, es = 0.f;                                                    \
        _Pragma("unroll") for (int d4 = 0; d4 < 8; d4++) {                           \
            ef = fmaf(e##SUF[d4].x, wf[4 * d4 + 0], ef);                             \
            ef = fmaf(e##SUF[d4].y, wf[4 * d4 + 1], ef);                             \
            ef = fmaf(e##SUF[d4].z, wf[4 * d4 + 2], ef);                             \
            ef = fmaf(e##SUF[d4].w, wf[4 * d4 + 3], ef);                             \
            es = fmaf(e##SUF[d4].x, ws[4 * d4 + 0], es);                             \
            es = fmaf(e##SUF[d4].y, ws[4 * d4 + 1], es);                             \
            es = fmaf(e##SUF[d4].z, ws[4 * d4 + 2], es);                             \
            es = fmaf(e##SUF[d4].w, ws[4 * d4 + 3], es);                             \
        }                                                                            \
        float xf = Pi + Q##SUF + ef;                                                 \
        float xs = Ri + S##SUF + es;                                                 \
        acc = fmaf(sigm(xf), softp(xs), acc);                                        \
    }

template <int LEAKY>
__global__ void k_agg(const float* __restrict__ h, const float* __restrict__ P,
                      const float* __restrict__ Q, const float* __restrict__ R,
                      const float* __restrict__ S, const float* __restrict__ eattr,
                      const float* __restrict__ Wfe, const float* __restrict__ Wse,
                      const int* __restrict__ rowptr, const int* __restrict__ src_s,
                      const int* __restrict__ eid_s, float* __restrict__ out, int N) {
    const int c = threadIdx.x;       // 128 threads, one channel each
    const int lane = c & 63;
    float wf[DDIM], ws[DDIM];
#pragma unroll
    for (int d = 0; d < DDIM; d++) {
        wf[d] = Wfe[d * CDIM + c];
        ws[d] = Wse[d * CDIM + c];
    }
    for (int i = blockIdx.x; i < N; i += gridDim.x) {
        const int e0 = rowptr[i], e1 = rowptr[i + 1];
        const float Pi = P[(size_t)i * CDIM + c], Ri = R[(size_t)i * CDIM + c];
        float acc = 0.f;
        for (int base = e0; base < e1; base += 64) {
            const int m = min(64, e1 - base);
            const int idx = base + (lane < m ? lane : 0);
            const int sL = src_s[idx];
            const int idL = eid_s[idx];
            float QA, SA, QB, SB;
            float4 eA[8], eB[8];
            EDGE_LOAD(A, 0)
            for (int j = 0; j < m; j += 2) {
                const bool hasB = (j + 1 < m);
                if (hasB) EDGE_LOAD(B, j + 1)
                EDGE_COMPUTE(A)
                if (j + 2 < m) EDGE_LOAD(A, j + 2)
                if (hasB) EDGE_COMPUTE(B)
            }
        }
        float v = h[(size_t)i * CDIM + c] + acc;
        if (LEAKY) v = lrelu(v);
        out[(size_t)i * CDIM + c] = v;
    }
}

// ---------------- pooling ----------------
__global__ void k_pool(const float* __restrict__ h2, const int* __restrict__ batch,
                       float* __restrict__ gsum, int* __restrict__ gcnt, int N) {
    int total = N * CDIM;
    int stride = gridDim.x * blockDim.x;
    for (int idx = blockIdx.x * blockDim.x + threadIdx.x; idx < total; idx += stride) {
        int n = idx >> 7, c = idx & (CDIM - 1);
        int g = batch[n];
        atomicAdd(&gsum[g * CDIM + c], h2[idx]);
        if (c == 0) atomicAdd(&gcnt[g], 1);
    }
}

// ---------------- head: out = sigmoid(leaky(pooled@fc1+b1)@fc2+b2) ----------------
__global__ void k_head(const float* __restrict__ gsum, const int* __restrict__ gcnt,
                       const int* __restrict__ y, const float* __restrict__ fc1W,
                       const float* __restrict__ fc1b, const float* __restrict__ fc2W,
                       const float* __restrict__ fc2b, float* __restrict__ out) {
    int g = blockIdx.x;
    int j = threadIdx.x;  // 64 threads (1 wave), first 32 compute
    int cnt = gcnt[g];
    float inv = 1.f / fmaxf((float)cnt, 1.f);
    float t = 0.f;
    if (j < 32) {
        t = fc1b[j];
        for (int k = 0; k < CDIM; k++) t = fmaf(gsum[g * CDIM + k] * inv, fc1W[k * 32 + j], t);
        if (cnt > 0) t += fc1W[(CDIM + y[g]) * 32 + j];  // one-hot part of pooled
        t = lrelu(t);
        t *= fc2W[j];
    }
#pragma unroll
    for (int off = 32; off > 0; off >>= 1) t += __shfl_down(t, off, 64);
    if (j == 0) out[g] = sigm(t + fc2b[0]);
}

// ---------------- launch ----------------
extern "C" void kernel_launch(void* const* d_in, const int* in_sizes, int n_in,
                              void* d_out, int out_size, void* d_ws, size_t ws_size,
                              hipStream_t stream) {
    const float* x = (const float*)d_in[0];
    const int* y = (const int*)d_in[1];
    const int* ei = (const int*)d_in[2];
    const float* eattr = (const float*)d_in[3];
    const int* batch = (const int*)d_in[4];
    const float* lin_W = (const float*)d_in[5];
    const float* lin_b = (const float*)d_in[6];
    const float* c1_Wf = (const float*)d_in[7];
    const float* c1_bf = (const float*)d_in[8];
    const float* c1_Ws = (const float*)d_in[9];
    const float* c1_bs = (const float*)d_in[10];
    const float* c2_Wf = (const float*)d_in[11];
    const float* c2_bf = (const float*)d_in[12];
    const float* c2_Ws = (const float*)d_in[13];
    const float* c2_bs = (const float*)d_in[14];
    const float* fc1_W = (const float*)d_in[15];
    const float* fc1_b = (const float*)d_in[16];
    const float* fc2_W = (const float*)d_in[17];
    const float* fc2_b = (const float*)d_in[18];
    float* out = (float*)d_out;

    const int N = in_sizes[0] / CDIM;   // 50000
    const int E = in_sizes[2] / 2;      // 800000
    const int G = in_sizes[1];          // 64
    const int NB = (N + 255) / 256;

    // workspace carve-up (256B aligned)
    char* ws = (char*)d_ws;
    size_t off = 0;
    auto alloc = [&](size_t bytes) {
        size_t p = off;
        off = (off + bytes + 255) & ~(size_t)255;
        return (void*)(ws + p);
    };
    float* h0 = (float*)alloc((size_t)N * CDIM * 4);
    float* h1 = (float*)alloc((size_t)N * CDIM * 4);
    float* P = (float*)alloc((size_t)N * CDIM * 4);
    float* Q = (float*)alloc((size_t)N * CDIM * 4);
    float* R = (float*)alloc((size_t)N * CDIM * 4);
    float* S = (float*)alloc((size_t)N * CDIM * 4);
    int* rowptr = (int*)alloc((size_t)(N + 1) * 4);
    int* counts = (int*)alloc((size_t)N * 4);
    int* cur = (int*)alloc((size_t)N * 4);
    int* bsum = (int*)alloc((size_t)NB * 4);
    int* boff = (int*)alloc((size_t)NB * 4);
    int* src_s = (int*)alloc((size_t)E * 4);
    int* eid_s = (int*)alloc((size_t)E * 4);
    float* gsum = (float*)alloc((size_t)G * CDIM * 4);
    int* gcnt = (int*)alloc((size_t)G * 4);

    hipMemsetAsync(counts, 0, (size_t)N * 4, stream);
    hipMemsetAsync(gsum, 0, (size_t)G * CDIM * 4, stream);
    hipMemsetAsync(gcnt, 0, (size_t)G * 4, stream);

    // CSR build
    k_hist<<<4096, 256, 0, stream>>>(ei, counts, E);
    k_scan1<<<NB, 256, 0, stream>>>(counts, rowptr, bsum, N);
    k_scan2<<<1, 256, 0, stream>>>(bsum, boff, rowptr + N, NB);
    k_scan3<<<(N + 255) / 256, 256, 0, stream>>>(rowptr, cur, boff, N);
    k_fill<<<4096, 256, 0, stream>>>(ei, cur, src_s, eid_s, E);

    // layer 1
    k_lin1<16><<<N / 16, CDIM, 0, stream>>>(x, y, batch, lin_W, lin_b, h0, N);

    // conv1
    k_gemm4<16><<<N / 16, CDIM, 0, stream>>>(h0, c1_Wf, c1_Ws, c1_bf, c1_bs, P, Q, R, S, N);
    k_agg<1><<<4096, CDIM, 0, stream>>>(h0, P, Q, R, S, eattr, c1_Wf + 256 * CDIM,
                                        c1_Ws + 256 * CDIM, rowptr, src_s, eid_s, h1, N);
    // conv2 (h2 overwrites h0 buffer)
    k_gemm4<16><<<N / 16, CDIM, 0, stream>>>(h1, c2_Wf, c2_Ws, c2_bf, c2_bs, P, Q, R, S, N);
    k_agg<0><<<4096, CDIM, 0, stream>>>(h1, P, Q, R, S, eattr, c2_Wf + 256 * CDIM,
                                        c2_Ws + 256 * CDIM, rowptr, src_s, eid_s, h0, N);

    // pool + head
    k_pool<<<4096, 256, 0, stream>>>(h0, batch, gsum, gcnt, N);
    k_head<<<G, 64, 0, stream>>>(gsum, gcnt, y, fc1_W, fc1_b, fc2_W, fc2_b, out);
}

// Round 3
// 1398.555 us; speedup vs baseline: 4.8802x; 4.8802x over previous
//
#include <hip/hip_runtime.h>
#include <math.h>

#define CDIM 128
#define DDIM 32
#define TB 32   // edges per LDS tile in k_agg

static __device__ __forceinline__ float lrelu(float v) { return v >= 0.f ? v : 0.01f * v; }
static __device__ __forceinline__ float sigm(float x) {
    return __builtin_amdgcn_rcpf(1.f + __expf(-x));
}
static __device__ __forceinline__ float softp(float x) {
    // stable softplus: max(x,0) + log(1+exp(-|x|))
    return fmaxf(x, 0.f) + __logf(1.f + __expf(-fabsf(x)));
}

// ---------------- CSR build ----------------
__global__ void k_hist(const int* __restrict__ ei, int* __restrict__ counts, int E) {
    int stride = gridDim.x * blockDim.x;
    for (int e = blockIdx.x * blockDim.x + threadIdx.x; e < E; e += stride)
        atomicAdd(&counts[ei[E + e]], 1);  // dst = row 1
}

__global__ void k_scan1(const int* __restrict__ counts, int* __restrict__ excl,
                        int* __restrict__ bsum, int N) {
    __shared__ int sm[256];
    int t = threadIdx.x, idx = blockIdx.x * 256 + t;
    int v = (idx < N) ? counts[idx] : 0;
    sm[t] = v; __syncthreads();
    for (int off = 1; off < 256; off <<= 1) {
        int x = (t >= off) ? sm[t - off] : 0;
        __syncthreads();
        sm[t] += x;
        __syncthreads();
    }
    if (idx < N) excl[idx] = sm[t] - v;
    if (t == 255) bsum[blockIdx.x] = sm[255];
}

__global__ void k_scan2(const int* __restrict__ bsum, int* __restrict__ boff,
                        int* __restrict__ rowptr_end, int NB) {
    __shared__ int sm[256];
    int t = threadIdx.x;
    int v = (t < NB) ? bsum[t] : 0;
    sm[t] = v; __syncthreads();
    for (int off = 1; off < 256; off <<= 1) {
        int x = (t >= off) ? sm[t - off] : 0;
        __syncthreads();
        sm[t] += x;
        __syncthreads();
    }
    if (t < NB) boff[t] = sm[t] - v;
    if (t == 255) *rowptr_end = sm[255];  // == E
}

__global__ void k_scan3(int* __restrict__ rowptr, int* __restrict__ cur,
                        const int* __restrict__ boff, int N) {
    int idx = blockIdx.x * blockDim.x + threadIdx.x;
    if (idx < N) {
        int v = rowptr[idx] + boff[idx >> 8];
        rowptr[idx] = v;
        cur[idx] = v;
    }
}

__global__ void k_fill(const int* __restrict__ ei, int* __restrict__ cur,
                       int* __restrict__ src_s, int* __restrict__ eid_s, int E) {
    int stride = gridDim.x * blockDim.x;
    for (int e = blockIdx.x * blockDim.x + threadIdx.x; e < E; e += stride) {
        int d = ei[E + e];
        int pos = atomicAdd(&cur[d], 1);
        src_s[pos] = ei[e];   // src = row 0
        eid_s[pos] = e;
    }
}

// ---------------- layer 1: h0 = leaky([x, onehot] @ lin_W + b) ----------------
template <int ROWS>
__global__ void k_lin1(const float* __restrict__ x, const int* __restrict__ y,
                       const int* __restrict__ batch, const float* __restrict__ W,
                       const float* __restrict__ b, float* __restrict__ h0, int N) {
    __shared__ float xs[ROWS][CDIM];
    int c = threadIdx.x;             // 128 threads
    int n0 = blockIdx.x * ROWS;
    for (int r = 0; r < ROWS; r++) xs[r][c] = x[(n0 + r) * CDIM + c];
    __syncthreads();
    float acc[ROWS];
#pragma unroll
    for (int r = 0; r < ROWS; r++) {
        int cls = y[batch[n0 + r]];
        acc[r] = b[c] + W[(CDIM + cls) * CDIM + c];  // one-hot row select
    }
    for (int k = 0; k < CDIM; k++) {
        float w = W[k * CDIM + c];
#pragma unroll
        for (int r = 0; r < ROWS; r++) acc[r] = fmaf(xs[r][k], w, acc[r]);
    }
    for (int r = 0; r < ROWS; r++) h0[(n0 + r) * CDIM + c] = lrelu(acc[r]);
}

// ---------------- per-conv node GEMMs: P=h@Wf_d+bf, Q=h@Wf_s, R=h@Ws_d+bs, S=h@Ws_s ----------------
template <int ROWS>
__global__ void k_gemm4(const float* __restrict__ h, const float* __restrict__ Wf,
                        const float* __restrict__ Ws, const float* __restrict__ bf,
                        const float* __restrict__ bs, float* __restrict__ P,
                        float* __restrict__ Q, float* __restrict__ R,
                        float* __restrict__ S, int N) {
    __shared__ float hs[ROWS][CDIM];
    int c = threadIdx.x;
    int n0 = blockIdx.x * ROWS;
    for (int r = 0; r < ROWS; r++) hs[r][c] = h[(n0 + r) * CDIM + c];
    __syncthreads();
    float ap[ROWS], aq[ROWS], ar[ROWS], asv[ROWS];
    float vbf = bf[c], vbs = bs[c];
#pragma unroll
    for (int r = 0; r < ROWS; r++) { ap[r] = vbf; aq[r] = 0.f; ar[r] = vbs; asv[r] = 0.f; }
    for (int k = 0; k < CDIM; k++) {
        float wp = Wf[k * CDIM + c];
        float wq = Wf[(CDIM + k) * CDIM + c];
        float wr = Ws[k * CDIM + c];
        float wsv = Ws[(CDIM + k) * CDIM + c];
#pragma unroll
        for (int r = 0; r < ROWS; r++) {
            float hv = hs[r][k];
            ap[r] = fmaf(hv, wp, ap[r]);
            aq[r] = fmaf(hv, wq, aq[r]);
            ar[r] = fmaf(hv, wr, ar[r]);
            asv[r] = fmaf(hv, wsv, asv[r]);
        }
    }
    for (int r = 0; r < ROWS; r++) {
        int o = (n0 + r) * CDIM + c;
        P[o] = ap[r]; Q[o] = aq[r]; R[o] = ar[r]; S[o] = asv[r];
    }
}

// ---------------- edge aggregation: LDS-staged eattr tiles, reg-resident weights ----------------
#define EDGE_DOT(J, EF, ES)                                   \
    {                                                         \
        float ef_ = 0.f, es_ = 0.f;                           \
        _Pragma("unroll") for (int d4 = 0; d4 < 8; d4++) {    \
            float4 v = se4[J][d4];                            \
            ef_ = fmaf(v.x, wf[4 * d4 + 0], ef_);             \
            ef_ = fmaf(v.y, wf[4 * d4 + 1], ef_);             \
            ef_ = fmaf(v.z, wf[4 * d4 + 2], ef_);             \
            ef_ = fmaf(v.w, wf[4 * d4 + 3], ef_);             \
            es_ = fmaf(v.x, ws[4 * d4 + 0], es_);             \
            es_ = fmaf(v.y, ws[4 * d4 + 1], es_);             \
            es_ = fmaf(v.z, ws[4 * d4 + 2], es_);             \
            es_ = fmaf(v.w, ws[4 * d4 + 3], es_);             \
        }                                                     \
        EF = ef_; ES = es_;                                   \
    }

template <int LEAKY>
__launch_bounds__(128, 2)
__global__ void k_agg(const float* __restrict__ h, const float* __restrict__ P,
                      const float* __restrict__ Q, const float* __restrict__ R,
                      const float* __restrict__ S, const float* __restrict__ eattr,
                      const float* __restrict__ Wfe, const float* __restrict__ Wse,
                      const int* __restrict__ rowptr, const int* __restrict__ src_s,
                      const int* __restrict__ eid_s, float* __restrict__ out, int N) {
    const int c = threadIdx.x;  // 128 threads, one channel each
    __shared__ float4 se4[TB][9];  // [edge][8 float4 of eattr], +1 pad vs bank conflicts
    __shared__ int ss[TB];
    // per-thread weight columns, forced register-resident by launch_bounds
    float wf[DDIM], ws[DDIM];
#pragma unroll
    for (int d = 0; d < DDIM; d++) {
        wf[d] = Wfe[d * CDIM + c];
        ws[d] = Wse[d * CDIM + c];
    }
    const int row = c >> 2, part = c & 3;  // staging role: 4 threads per edge row
    for (int i = blockIdx.x; i < N; i += gridDim.x) {
        const int e0 = rowptr[i], e1 = rowptr[i + 1];
        const float Pi = P[(size_t)i * CDIM + c], Ri = R[(size_t)i * CDIM + c];
        float acc = 0.f;
        for (int base = e0; base < e1; base += TB) {
            const int m = min(TB, e1 - base);
            if (c < m) ss[c] = src_s[base + c];
            if (row < m) {
                int eid = eid_s[base + row];
                const float4* p = reinterpret_cast<const float4*>(eattr + (size_t)eid * DDIM);
                se4[row][2 * part] = p[2 * part];
                se4[row][2 * part + 1] = p[2 * part + 1];
            }
            __syncthreads();
            int j = 0;
            for (; j + 1 < m; j += 2) {
                int s0 = ss[j], s1 = ss[j + 1];
                float Q0 = Q[(size_t)s0 * CDIM + c];
                float S0 = S[(size_t)s0 * CDIM + c];
                float Q1 = Q[(size_t)s1 * CDIM + c];
                float S1 = S[(size_t)s1 * CDIM + c];
                float ef0, es0, ef1, es1;
                EDGE_DOT(j, ef0, es0)
                EDGE_DOT(j + 1, ef1, es1)
                acc = fmaf(sigm(Pi + Q0 + ef0), softp(Ri + S0 + es0), acc);
                acc = fmaf(sigm(Pi + Q1 + ef1), softp(Ri + S1 + es1), acc);
            }
            if (j < m) {
                int s0 = ss[j];
                float Q0 = Q[(size_t)s0 * CDIM + c];
                float S0 = S[(size_t)s0 * CDIM + c];
                float ef0, es0;
                EDGE_DOT(j, ef0, es0)
                acc = fmaf(sigm(Pi + Q0 + ef0), softp(Ri + S0 + es0), acc);
            }
            __syncthreads();
        }
        float v = h[(size_t)i * CDIM + c] + acc;
        if (LEAKY) v = lrelu(v);
        out[(size_t)i * CDIM + c] = v;
    }
}

// ---------------- pooling: batch is sorted -> per-group streaming, no atomics ----------------
__global__ void k_gbound(const int* __restrict__ batch, int* __restrict__ gstart,
                         int N, int G) {
    int g = threadIdx.x;
    if (g > G) return;
    int lo = 0, hi = N;
    while (lo < hi) {
        int mid = (lo + hi) >> 1;
        if (batch[mid] < g) lo = mid + 1; else hi = mid;
    }
    gstart[g] = lo;
}

__global__ void k_pool(const float* __restrict__ h2, const int* __restrict__ gstart,
                       float* __restrict__ gsum, int* __restrict__ gcnt) {
    int g = blockIdx.x;
    int c = threadIdx.x;  // 128 threads
    int n0 = gstart[g], n1 = gstart[g + 1];
    float acc = 0.f;
    for (int n = n0; n < n1; n++) acc += h2[(size_t)n * CDIM + c];
    gsum[g * CDIM + c] = acc;
    if (c == 0) gcnt[g] = n1 - n0;
}

// ---------------- head: out = sigmoid(leaky(pooled@fc1+b1)@fc2+b2) ----------------
__global__ void k_head(const float* __restrict__ gsum, const int* __restrict__ gcnt,
                       const int* __restrict__ y, const float* __restrict__ fc1W,
                       const float* __restrict__ fc1b, const float* __restrict__ fc2W,
                       const float* __restrict__ fc2b, float* __restrict__ out) {
    int g = blockIdx.x;
    int j = threadIdx.x;  // 64 threads (1 wave), first 32 compute
    int cnt = gcnt[g];
    float inv = 1.f / fmaxf((float)cnt, 1.f);
    float t = 0.f;
    if (j < 32) {
        t = fc1b[j];
        for (int k = 0; k < CDIM; k++) t = fmaf(gsum[g * CDIM + k] * inv, fc1W[k * 32 + j], t);
        if (cnt > 0) t += fc1W[(CDIM + y[g]) * 32 + j];  // one-hot part of pooled
        t = lrelu(t);
        t *= fc2W[j];
    }
#pragma unroll
    for (int off = 32; off > 0; off >>= 1) t += __shfl_down(t, off, 64);
    if (j == 0) out[g] = sigm(t + fc2b[0]);
}

// ---------------- launch ----------------
extern "C" void kernel_launch(void* const* d_in, const int* in_sizes, int n_in,
                              void* d_out, int out_size, void* d_ws, size_t ws_size,
                              hipStream_t stream) {
    const float* x = (const float*)d_in[0];
    const int* y = (const int*)d_in[1];
    const int* ei = (const int*)d_in[2];
    const float* eattr = (const float*)d_in[3];
    const int* batch = (const int*)d_in[4];
    const float* lin_W = (const float*)d_in[5];
    const float* lin_b = (const float*)d_in[6];
    const float* c1_Wf = (const float*)d_in[7];
    const float* c1_bf = (const float*)d_in[8];
    const float* c1_Ws = (const float*)d_in[9];
    const float* c1_bs = (const float*)d_in[10];
    const float* c2_Wf = (const float*)d_in[11];
    const float* c2_bf = (const float*)d_in[12];
    const float* c2_Ws = (const float*)d_in[13];
    const float* c2_bs = (const float*)d_in[14];
    const float* fc1_W = (const float*)d_in[15];
    const float* fc1_b = (const float*)d_in[16];
    const float* fc2_W = (const float*)d_in[17];
    const float* fc2_b = (const float*)d_in[18];
    float* out = (float*)d_out;

    const int N = in_sizes[0] / CDIM;   // 50000
    const int E = in_sizes[2] / 2;      // 800000
    const int G = in_sizes[1];          // 64
    const int NB = (N + 255) / 256;

    // workspace carve-up (256B aligned)
    char* ws = (char*)d_ws;
    size_t off = 0;
    auto alloc = [&](size_t bytes) {
        size_t p = off;
        off = (off + bytes + 255) & ~(size_t)255;
        return (void*)(ws + p);
    };
    float* h0 = (float*)alloc((size_t)N * CDIM * 4);
    float* h1 = (float*)alloc((size_t)N * CDIM * 4);
    float* P = (float*)alloc((size_t)N * CDIM * 4);
    float* Q = (float*)alloc((size_t)N * CDIM * 4);
    float* R = (float*)alloc((size_t)N * CDIM * 4);
    float* S = (float*)alloc((size_t)N * CDIM * 4);
    int* rowptr = (int*)alloc((size_t)(N + 1) * 4);
    int* counts = (int*)alloc((size_t)N * 4);
    int* cur = (int*)alloc((size_t)N * 4);
    int* bsum = (int*)alloc((size_t)NB * 4);
    int* boff = (int*)alloc((size_t)NB * 4);
    int* src_s = (int*)alloc((size_t)E * 4);
    int* eid_s = (int*)alloc((size_t)E * 4);
    float* gsum = (float*)alloc((size_t)G * CDIM * 4);
    int* gcnt = (int*)alloc((size_t)G * 4);
    int* gstart = (int*)alloc((size_t)(G + 1) * 4);

    hipMemsetAsync(counts, 0, (size_t)N * 4, stream);

    // CSR build
    k_hist<<<4096, 256, 0, stream>>>(ei, counts, E);
    k_scan1<<<NB, 256, 0, stream>>>(counts, rowptr, bsum, N);
    k_scan2<<<1, 256, 0, stream>>>(bsum, boff, rowptr + N, NB);
    k_scan3<<<(N + 255) / 256, 256, 0, stream>>>(rowptr, cur, boff, N);
    k_fill<<<4096, 256, 0, stream>>>(ei, cur, src_s, eid_s, E);
    k_gbound<<<1, 128, 0, stream>>>(batch, gstart, N, G);

    // layer 1
    k_lin1<16><<<N / 16, CDIM, 0, stream>>>(x, y, batch, lin_W, lin_b, h0, N);

    // conv1
    k_gemm4<16><<<N / 16, CDIM, 0, stream>>>(h0, c1_Wf, c1_Ws, c1_bf, c1_bs, P, Q, R, S, N);
    k_agg<1><<<4096, CDIM, 0, stream>>>(h0, P, Q, R, S, eattr, c1_Wf + 256 * CDIM,
                                        c1_Ws + 256 * CDIM, rowptr, src_s, eid_s, h1, N);
    // conv2 (h2 overwrites h0 buffer)
    k_gemm4<16><<<N / 16, CDIM, 0, stream>>>(h1, c2_Wf, c2_Ws, c2_bf, c2_bs, P, Q, R, S, N);
    k_agg<0><<<4096, CDIM, 0, stream>>>(h1, P, Q, R, S, eattr, c2_Wf + 256 * CDIM,
                                        c2_Ws + 256 * CDIM, rowptr, src_s, eid_s, h0, N);

    // pool + head
    k_pool<<<G, CDIM, 0, stream>>>(h0, gstart, gsum, gcnt);
    k_head<<<G, 64, 0, stream>>>(gsum, gcnt, y, fc1_W, fc1_b, fc2_W, fc2_b, out);
}